// Round 11
// baseline (124.021 us; speedup 1.0000x reference)
//
#include <hip/hip_runtime.h>
#include <hip/hip_bf16.h>

#define N_ROWS 8192
#define DIM 256
#define TEMP_INV 20.0f
// exp(cos/T) = exp2(cos * 20*log2(e)); anchor rows are PRE-SCALED by this so
// the fused epilogue is a bare v_exp on the MFMA accumulator.
#define EXP_SCALE 28.853900817779268f

typedef __attribute__((ext_vector_type(8))) short bf16x8;
typedef __attribute__((ext_vector_type(4))) float f32x4;

// ---------------------------------------------------------------------------
// 1) Merged prep (unchanged from R10).
// ---------------------------------------------------------------------------
__global__ void __launch_bounds__(256) prep_kernel(
    const float* __restrict__ anc, const float* __restrict__ pos,
    const float* __restrict__ neg, __hip_bfloat16* __restrict__ a_n,
    __hip_bfloat16* __restrict__ p_k, __hip_bfloat16* __restrict__ n_k,
    float* __restrict__ diag, float* __restrict__ rowsum,
    float* __restrict__ out) {
  __shared__ __align__(16) __hip_bfloat16 t[32 * DIM];   // 16KB (panel path)
  const int lane = threadIdx.x & 63;
  const int w = threadIdx.x >> 6;

  if (blockIdx.x < 2048) {                   // ---- anchor rows ----
    int wid = blockIdx.x * 4 + w;            // row 0..8191
    float4 a = reinterpret_cast<const float4*>(anc + (size_t)wid * DIM)[lane];
    float4 p = reinterpret_cast<const float4*>(pos + (size_t)wid * DIM)[lane];
    float d  = a.x * p.x + a.y * p.y + a.z * p.z + a.w * p.w;
    float na = a.x * a.x + a.y * a.y + a.z * a.z + a.w * a.w;
    float np = p.x * p.x + p.y * p.y + p.z * p.z + p.w * p.w;
#pragma unroll
    for (int m = 32; m; m >>= 1) {
      d  += __shfl_xor(d, m);
      na += __shfl_xor(na, m);
      np += __shfl_xor(np, m);
    }
    float rna = fmaxf(sqrtf(na), 1e-8f);
    float scale = EXP_SCALE / rna;
    union { __hip_bfloat16 h[4]; uint2 u; } pk;
    pk.h[0] = __float2bfloat16(a.x * scale);
    pk.h[1] = __float2bfloat16(a.y * scale);
    pk.h[2] = __float2bfloat16(a.z * scale);
    pk.h[3] = __float2bfloat16(a.w * scale);
    reinterpret_cast<uint2*>(a_n + (size_t)wid * DIM)[lane] = pk.u;
    if (lane == 0) {
      diag[wid] = TEMP_INV * d / (rna * fmaxf(sqrtf(np), 1e-8f));
      rowsum[wid] = 0.f;
    }
    return;
  }
  // ---- P/N k-major panels ----
  const int b = blockIdx.x - 2048;           // 0..511
  if (b == 511 && threadIdx.x == 0) out[0] = 0.f;
  const float* src = (b < 256) ? pos : neg;
  __hip_bfloat16* dst = (b < 256) ? p_k : n_k;
  const int pb = b & 255;
#pragma unroll
  for (int i = 0; i < 8; ++i) {
    int r = i * 4 + w;                       // row (col of B) within panel
    float4 v = reinterpret_cast<const float4*>(src + (size_t)(pb * 32 + r) * DIM)[lane];
    float ss = v.x * v.x + v.y * v.y + v.z * v.z + v.w * v.w;
#pragma unroll
    for (int m = 32; m; m >>= 1) ss += __shfl_xor(ss, m);
    float scale = 1.0f / fmaxf(sqrtf(ss), 1e-8f);
    union { __hip_bfloat16 h[4]; uint2 u; } pk;
    pk.h[0] = __float2bfloat16(v.x * scale);
    pk.h[1] = __float2bfloat16(v.y * scale);
    pk.h[2] = __float2bfloat16(v.z * scale);
    pk.h[3] = __float2bfloat16(v.w * scale);
    // lane holds k = 4*lane..4*lane+3  ->  k0 = lane>>1, half = lane&1
    char* p = (char*)t + ((((lane >> 1) * 32) + r) << 4) + ((lane & 1) << 3);
    *reinterpret_cast<uint2*>(p) = pk.u;
  }
  __syncthreads();
  const uint4* ts = reinterpret_cast<const uint4*>(t);
  uint4* outp = reinterpret_cast<uint4*>(dst + (size_t)pb * (32 * DIM));
#pragma unroll
  for (int j = 0; j < 4; ++j)
    outp[threadIdx.x + j * 256] = ts[threadIdx.x + j * 256];
}

// ---------------------------------------------------------------------------
// 2) Fused GEMM + row-sum(exp2) -- ABLATION PAIR (within-probe A/B).
//    MODE 0: R10 control (real output).
//    MODE 4: identical MFMA+EPI instruction stream, ALL memory/sync removed
//            (bf pinned from regs; no LDS/STAGE/barrier/vmcnt; psum asm-sunk;
//            no stores). Measures whether the per-wave stream alone can
//            saturate the MFMA pipe at 2 waves/SIMD. Rule-17 discipline:
//            every otherwise-dead value is kept live via asm volatile sinks.
// ---------------------------------------------------------------------------
template <int MODE>
__global__ void __launch_bounds__(512, 2) fused_kernel(
    const __hip_bfloat16* __restrict__ a_n, const __hip_bfloat16* __restrict__ p_k,
    const __hip_bfloat16* __restrict__ n_k, float* __restrict__ rowsum) {
  constexpr bool USE_LDS = (MODE != 4);
  __shared__ __align__(16) char smem[4 * 16384];   // ring of 4 x 16KB panels
  const int tid  = threadIdx.x;
  const int lane = tid & 63;
  const int w    = tid >> 6;          // 0..7
  const int rb   = blockIdx.x >> 5;   // 0..15 (512 rows each)
  const int cc   = blockIdx.x & 31;   // 0..31 (512 cols = 16 panels each)
  const char* B = (const char*)((cc < 16)
      ? (p_k + (size_t)cc * 16 * (32 * DIM))
      : (n_k + (size_t)(cc - 16) * 16 * (32 * DIM)));
  const int row0 = rb * 512 + w * 64;
  const int ar = lane & 15;           // fragment row/col index
  const int g  = lane >> 4;           // k-group within fragment
  const int vbase = (g << 9) + (ar << 4);  // lane byte-offset within a panel

  // A fragments: 64 rows x K=256, pinned resident.
  bf16x8 afrag[4][8];
#pragma unroll
  for (int rf = 0; rf < 4; ++rf)
#pragma unroll
    for (int kk = 0; kk < 8; ++kk) {
      afrag[rf][kk] = *reinterpret_cast<const bf16x8*>(
          a_n + (size_t)(row0 + rf * 16 + ar) * DIM + kk * 32 + g * 8);
      asm volatile("" : "+v"(afrag[rf][kk]));   // non-remat def: stays resident
    }

#define STAGE(p)                                                               \
  {                                                                            \
    _Pragma("unroll")                                                          \
    for (int j = 0; j < 2; ++j) {                                              \
      const int L = (w << 1) | j;                                              \
      const char* src = B + ((size_t)(p) << 14) + (L << 10) + (lane << 4);     \
      char* dst = (char*)smem + (((p) & 3) << 14) + (L << 10);                 \
      __builtin_amdgcn_global_load_lds(                                        \
          (const __attribute__((address_space(1))) void*)src,                  \
          (__attribute__((address_space(3))) void*)dst, 16, 0, 0);             \
    }                                                                          \
  }

#define LDV(p) (*reinterpret_cast<const bf16x8*>(p))
#define MM(A, Bf, C) __builtin_amdgcn_mfma_f32_16x16x32_bf16((A), (Bf), (C), 0, 0, 0)
#define EPI(ACCP, e) \
  psum[(e) >> 2][(e) & 3] += __builtin_amdgcn_exp2f(ACCP[(e) >> 2][(e) & 3])

  // One cluster: 32 MFMA + 16 epilogue elems of the PREVIOUS cluster,
  // interleaved; bf0/bf1 refilled (LDS modes only) right after last use.
#define CLUSTER(ACCC, ACCP, NEXTB)                                             \
  {                                                                            \
    ACCC[0] = MM(afrag[0][0], bf0[0], zerov);                                  \
    ACCC[1] = MM(afrag[1][0], bf0[0], zerov);                                  \
    ACCC[2] = MM(afrag[2][0], bf0[0], zerov);                                  \
    ACCC[3] = MM(afrag[3][0], bf0[0], zerov);                                  \
    EPI(ACCP, 0); EPI(ACCP, 1);                                                \
    ACCC[0] = MM(afrag[0][1], bf0[1], ACCC[0]);                                \
    ACCC[1] = MM(afrag[1][1], bf0[1], ACCC[1]);                                \
    ACCC[2] = MM(afrag[2][1], bf0[1], ACCC[2]);                                \
    ACCC[3] = MM(afrag[3][1], bf0[1], ACCC[3]);                                \
    EPI(ACCP, 2); EPI(ACCP, 3);                                                \
    ACCC[0] = MM(afrag[0][2], bf0[2], ACCC[0]);                                \
    ACCC[1] = MM(afrag[1][2], bf0[2], ACCC[1]);                                \
    ACCC[2] = MM(afrag[2][2], bf0[2], ACCC[2]);                                \
    ACCC[3] = MM(afrag[3][2], bf0[2], ACCC[3]);                                \
    EPI(ACCP, 4); EPI(ACCP, 5);                                                \
    ACCC[0] = MM(afrag[0][3], bf0[3], ACCC[0]);                                \
    ACCC[1] = MM(afrag[1][3], bf0[3], ACCC[1]);                                \
    ACCC[2] = MM(afrag[2][3], bf0[3], ACCC[2]);                                \
    ACCC[3] = MM(afrag[3][3], bf0[3], ACCC[3]);                                \
    EPI(ACCP, 6); EPI(ACCP, 7);                                                \
    if (USE_LDS) {                                                             \
      bf0[0] = LDV((NEXTB));                                                   \
      bf0[1] = LDV((NEXTB) + 2048);                                            \
      bf0[2] = LDV((NEXTB) + 4096);                                            \
      bf0[3] = LDV((NEXTB) + 6144);                                            \
    }                                                                          \
    ACCC[0] = MM(afrag[0][4], bf1[0], ACCC[0]);                                \
    ACCC[1] = MM(afrag[1][4], bf1[0], ACCC[1]);                                \
    ACCC[2] = MM(afrag[2][4], bf1[0], ACCC[2]);                                \
    ACCC[3] = MM(afrag[3][4], bf1[0], ACCC[3]);                                \
    EPI(ACCP, 8); EPI(ACCP, 9);                                                \
    ACCC[0] = MM(afrag[0][5], bf1[1], ACCC[0]);                                \
    ACCC[1] = MM(afrag[1][5], bf1[1], ACCC[1]);                                \
    ACCC[2] = MM(afrag[2][5], bf1[1], ACCC[2]);                                \
    ACCC[3] = MM(afrag[3][5], bf1[1], ACCC[3]);                                \
    EPI(ACCP, 10); EPI(ACCP, 11);                                              \
    ACCC[0] = MM(afrag[0][6], bf1[2], ACCC[0]);                                \
    ACCC[1] = MM(afrag[1][6], bf1[2], ACCC[1]);                                \
    ACCC[2] = MM(afrag[2][6], bf1[2], ACCC[2]);                                \
    ACCC[3] = MM(afrag[3][6], bf1[2], ACCC[3]);                                \
    EPI(ACCP, 12); EPI(ACCP, 13);                                              \
    ACCC[0] = MM(afrag[0][7], bf1[3], ACCC[0]);                                \
    ACCC[1] = MM(afrag[1][7], bf1[3], ACCC[1]);                                \
    ACCC[2] = MM(afrag[2][7], bf1[3], ACCC[2]);                                \
    ACCC[3] = MM(afrag[3][7], bf1[3], ACCC[3]);                                \
    EPI(ACCP, 14); EPI(ACCP, 15);                                              \
    if (USE_LDS) {                                                             \
      bf1[0] = LDV((NEXTB) + 8192);                                            \
      bf1[1] = LDV((NEXTB) + 10240);                                           \
      bf1[2] = LDV((NEXTB) + 12288);                                           \
      bf1[3] = LDV((NEXTB) + 14336);                                           \
    }                                                                          \
  }

  float psum[4][4];
#pragma unroll
  for (int rf = 0; rf < 4; ++rf)
#pragma unroll
    for (int q = 0; q < 4; ++q) psum[rf][q] = 0.f;

  const f32x4 zerov = {0.f, 0.f, 0.f, 0.f};
  bf16x8 bf0[4], bf1[4];
  f32x4 accA[4], accB[4];
  accB[0] = zerov; accB[1] = zerov; accB[2] = zerov; accB[3] = zerov;  // dummy

  if (USE_LDS) {
    STAGE(0);
    STAGE(1);
    STAGE(2);   // 6 loads/wave outstanding
    asm volatile("s_waitcnt vmcnt(4)" ::: "memory");   // own panel-0 loads done
    __builtin_amdgcn_s_barrier();                      // panel 0 fully staged
    const char* pb = smem + vbase;
    bf0[0] = LDV(pb);          bf0[1] = LDV(pb + 2048);
    bf0[2] = LDV(pb + 4096);   bf0[3] = LDV(pb + 6144);
    bf1[0] = LDV(pb + 8192);   bf1[1] = LDV(pb + 10240);
    bf1[2] = LDV(pb + 12288);  bf1[3] = LDV(pb + 14336);
  } else {
    // MODE 4: B operands pinned from registers -- no memory in the loop.
#pragma unroll
    for (int i = 0; i < 4; ++i) {
      bf0[i] = afrag[0][i];
      bf1[i] = afrag[0][i + 4];
    }
  }

  for (int it = 0; it < 16; ++it) {
    if (USE_LDS) {
      if (it <= 13) asm volatile("s_waitcnt vmcnt(2)" ::: "memory");
      else          asm volatile("s_waitcnt vmcnt(0)" ::: "memory");
      __builtin_amdgcn_s_barrier();
    }
    const char* pbase  = smem + ((it & 3) << 14) + vbase;
    const char* npbase = smem + (((it + 1) & 3) << 14) + vbase;
    CLUSTER(accA, accB, pbase + 256);   // (it,cf0); refill <- (it,cf1)
    if (USE_LDS) { if (it <= 12) STAGE(it + 3); }
    CLUSTER(accB, accA, npbase);        // (it,cf1); refill <- (it+1,cf0)
  }
  // Final epilogue for the last cf1 cluster.
#pragma unroll
  for (int e = 0; e < 16; ++e) { EPI(accB, e); }

  if (MODE == 0) {
    // Reduce over the 16 column-lanes; -1.0 compensates the dummy epilogue.
#pragma unroll
    for (int rf = 0; rf < 4; ++rf)
#pragma unroll
      for (int q = 0; q < 4; ++q) {
        float s = psum[rf][q] - 1.0f;
        s += __shfl_xor(s, 1);
        s += __shfl_xor(s, 2);
        s += __shfl_xor(s, 4);
        s += __shfl_xor(s, 8);
        if (ar == 0)
          atomicAdd(rowsum + row0 + rf * 16 + g * 4 + q, s);
      }
  } else {
    // Diagnostic mode: keep the whole computation live, write nothing.
#pragma unroll
    for (int rf = 0; rf < 4; ++rf)
#pragma unroll
      for (int q = 0; q < 4; ++q)
        asm volatile("" :: "v"(psum[rf][q]));
  }
#undef STAGE
#undef CLUSTER
#undef EPI
#undef MM
#undef LDV
}

// ---------------------------------------------------------------------------
// 3) loss (unchanged from R10).
// ---------------------------------------------------------------------------
__global__ void __launch_bounds__(512) loss_kernel(
    const float* __restrict__ rowsum, const float* __restrict__ diag,
    float* __restrict__ out) {
  __shared__ float sh[8];
  int i = blockIdx.x * 512 + threadIdx.x;    // exactly covers 8192 rows
  float acc = logf(rowsum[i]) - diag[i];
#pragma unroll
  for (int m = 32; m; m >>= 1) acc += __shfl_xor(acc, m);
  if ((threadIdx.x & 63) == 0) sh[threadIdx.x >> 6] = acc;
  __syncthreads();
  if (threadIdx.x == 0) {
    float t = 0.f;
#pragma unroll
    for (int j = 0; j < 8; ++j) t += sh[j];
    atomicAdd(out, t / (float)N_ROWS);
  }
}

// ---------------------------------------------------------------------------
extern "C" void kernel_launch(void* const* d_in, const int* in_sizes, int n_in,
                              void* d_out, int out_size, void* d_ws, size_t ws_size,
                              hipStream_t stream) {
  const float* anc = (const float*)d_in[0];
  const float* pos = (const float*)d_in[1];
  const float* neg = (const float*)d_in[2];
  char* ws = (char*)d_ws;
  __hip_bfloat16* a_n = (__hip_bfloat16*)ws;                 // [8192][256] bf16 row-major
  __hip_bfloat16* p_k = a_n + (size_t)N_ROWS * DIM;          // k-major panels
  __hip_bfloat16* n_k = p_k + (size_t)N_ROWS * DIM;
  float* diag = (float*)(ws + (size_t)3 * N_ROWS * DIM * 2); // 8192 f32
  float* rowsum = diag + N_ROWS;                             // 8192 f32
  float* out = (float*)d_out;

  prep_kernel<<<2048 + 512, 256, 0, stream>>>(anc, pos, neg, a_n, p_k, n_k, diag, rowsum, out);
  fused_kernel<0><<<16 * 32, 512, 0, stream>>>(a_n, p_k, n_k, rowsum);  // control (real)
  fused_kernel<4><<<16 * 32, 512, 0, stream>>>(a_n, p_k, n_k, rowsum);  // diag: pure MFMA+EPI stream
  loss_kernel<<<16, 512, 0, stream>>>(rowsum, diag, out);
}

// Round 12
// 89.303 us; speedup vs baseline: 1.3888x; 1.3888x over previous
//
#include <hip/hip_runtime.h>
#include <hip/hip_bf16.h>

#define N_ROWS 8192
#define DIM 256
#define TEMP_INV 20.0f
// exp(cos/T) = exp2(cos * 20*log2(e)); anchor rows are PRE-SCALED by this so
// the fused epilogue is a bare v_exp on the MFMA accumulator.
#define EXP_SCALE 28.853900817779268f

typedef __attribute__((ext_vector_type(8))) short bf16x8;
typedef __attribute__((ext_vector_type(4))) float f32x4;

// ---------------------------------------------------------------------------
// 1) Merged prep (unchanged from R10).
// ---------------------------------------------------------------------------
__global__ void __launch_bounds__(256) prep_kernel(
    const float* __restrict__ anc, const float* __restrict__ pos,
    const float* __restrict__ neg, __hip_bfloat16* __restrict__ a_n,
    __hip_bfloat16* __restrict__ p_k, __hip_bfloat16* __restrict__ n_k,
    float* __restrict__ diag, float* __restrict__ rowsum,
    float* __restrict__ out) {
  __shared__ __align__(16) __hip_bfloat16 t[32 * DIM];   // 16KB (panel path)
  const int lane = threadIdx.x & 63;
  const int w = threadIdx.x >> 6;

  if (blockIdx.x < 2048) {                   // ---- anchor rows ----
    int wid = blockIdx.x * 4 + w;            // row 0..8191
    float4 a = reinterpret_cast<const float4*>(anc + (size_t)wid * DIM)[lane];
    float4 p = reinterpret_cast<const float4*>(pos + (size_t)wid * DIM)[lane];
    float d  = a.x * p.x + a.y * p.y + a.z * p.z + a.w * p.w;
    float na = a.x * a.x + a.y * a.y + a.z * a.z + a.w * a.w;
    float np = p.x * p.x + p.y * p.y + p.z * p.z + p.w * p.w;
#pragma unroll
    for (int m = 32; m; m >>= 1) {
      d  += __shfl_xor(d, m);
      na += __shfl_xor(na, m);
      np += __shfl_xor(np, m);
    }
    float rna = fmaxf(sqrtf(na), 1e-8f);
    float scale = EXP_SCALE / rna;
    union { __hip_bfloat16 h[4]; uint2 u; } pk;
    pk.h[0] = __float2bfloat16(a.x * scale);
    pk.h[1] = __float2bfloat16(a.y * scale);
    pk.h[2] = __float2bfloat16(a.z * scale);
    pk.h[3] = __float2bfloat16(a.w * scale);
    reinterpret_cast<uint2*>(a_n + (size_t)wid * DIM)[lane] = pk.u;
    if (lane == 0) {
      diag[wid] = TEMP_INV * d / (rna * fmaxf(sqrtf(np), 1e-8f));
      rowsum[wid] = 0.f;
    }
    return;
  }
  // ---- P/N k-major panels ----
  const int b = blockIdx.x - 2048;           // 0..511
  if (b == 511 && threadIdx.x == 0) out[0] = 0.f;
  const float* src = (b < 256) ? pos : neg;
  __hip_bfloat16* dst = (b < 256) ? p_k : n_k;
  const int pb = b & 255;
#pragma unroll
  for (int i = 0; i < 8; ++i) {
    int r = i * 4 + w;                       // row (col of B) within panel
    float4 v = reinterpret_cast<const float4*>(src + (size_t)(pb * 32 + r) * DIM)[lane];
    float ss = v.x * v.x + v.y * v.y + v.z * v.z + v.w * v.w;
#pragma unroll
    for (int m = 32; m; m >>= 1) ss += __shfl_xor(ss, m);
    float scale = 1.0f / fmaxf(sqrtf(ss), 1e-8f);
    union { __hip_bfloat16 h[4]; uint2 u; } pk;
    pk.h[0] = __float2bfloat16(v.x * scale);
    pk.h[1] = __float2bfloat16(v.y * scale);
    pk.h[2] = __float2bfloat16(v.z * scale);
    pk.h[3] = __float2bfloat16(v.w * scale);
    // lane holds k = 4*lane..4*lane+3  ->  k0 = lane>>1, half = lane&1
    char* p = (char*)t + ((((lane >> 1) * 32) + r) << 4) + ((lane & 1) << 3);
    *reinterpret_cast<uint2*>(p) = pk.u;
  }
  __syncthreads();
  const uint4* ts = reinterpret_cast<const uint4*>(t);
  uint4* outp = reinterpret_cast<uint4*>(dst + (size_t)pb * (32 * DIM));
#pragma unroll
  for (int j = 0; j < 4; ++j)
    outp[threadIdx.x + j * 256] = ts[threadIdx.x + j * 256];
}

// ---------------------------------------------------------------------------
// 2) Fused GEMM + row-sum(exp2) -- faithful m201 8-phase port.
//    R11 ablation: pure MFMA+EPI stream = 39.6us (84% of pipe) at the SAME
//    2 waves/SIMD ==> the +34us is B-delivery/sync. Fix per m196/m201: FINE
//    phase interleave. Per panel (32 cols, K=256), 4 phases of 16 MFMA:
//      {4x ds_read_b128 (this phase's B-quad); [EPI slab of prev acc in the
//       read shadow]; [STAGE in P0]; s_barrier; s_waitcnt lgkmcnt(0);
//       sched_barrier(0) [rule 18]; setprio(1); 16 MFMA; setprio(0);
//       s_barrier}
//    vmcnt counted ONCE per panel at P3 (steady 4, tail 2/0 -- never 0 in
//    steady state); ring-4 LDS slots; STAGE(it+3) in P0 shadow overwrites
//    slot (it-1)&3 whose reads retired >=2 barriers earlier.
//    acc zero-init via MFMA C=zerov on each cf's first quad; EPI slabs:
//    accA (done end P1) -> P2 shadow; accB (done end P3) -> next P0 shadow
//    (first-panel dummy exp2(0)=1 compensated by -1 at reduction).
//    k-major panels -> ds_reads linear-in-lane, 0 conflicts (R4-R11).
//    MFMA 16x16x32_bf16 C layout: col=lane&15, row=(lane>>4)*4+q  [verified].
// ---------------------------------------------------------------------------
__global__ void __launch_bounds__(512, 2) fused_kernel(
    const __hip_bfloat16* __restrict__ a_n, const __hip_bfloat16* __restrict__ p_k,
    const __hip_bfloat16* __restrict__ n_k, float* __restrict__ rowsum) {
  __shared__ __align__(16) char smem[4 * 16384];   // ring of 4 x 16KB panels
  const int tid  = threadIdx.x;
  const int lane = tid & 63;
  const int w    = tid >> 6;          // 0..7
  const int rb   = blockIdx.x >> 5;   // 0..15 (512 rows each)
  const int cc   = blockIdx.x & 31;   // 0..31 (512 cols = 16 panels each)
  const char* B = (const char*)((cc < 16)
      ? (p_k + (size_t)cc * 16 * (32 * DIM))
      : (n_k + (size_t)(cc - 16) * 16 * (32 * DIM)));
  const int row0 = rb * 512 + w * 64;
  const int ar = lane & 15;           // fragment row/col index
  const int g  = lane >> 4;           // k-group within fragment
  const int vbase = (g << 9) + (ar << 4);  // lane byte-offset within a panel

  // A fragments: 64 rows x K=256, pinned resident.
  bf16x8 afrag[4][8];
#pragma unroll
  for (int rf = 0; rf < 4; ++rf)
#pragma unroll
    for (int kk = 0; kk < 8; ++kk) {
      afrag[rf][kk] = *reinterpret_cast<const bf16x8*>(
          a_n + (size_t)(row0 + rf * 16 + ar) * DIM + kk * 32 + g * 8);
      asm volatile("" : "+v"(afrag[rf][kk]));   // non-remat def: stays resident
    }

#define STAGE(p)                                                               \
  {                                                                            \
    _Pragma("unroll")                                                          \
    for (int j = 0; j < 2; ++j) {                                              \
      const int L = (w << 1) | j;                                              \
      const char* src = B + ((size_t)(p) << 14) + (L << 10) + (lane << 4);     \
      char* dst = (char*)smem + (((p) & 3) << 14) + (L << 10);                 \
      __builtin_amdgcn_global_load_lds(                                        \
          (const __attribute__((address_space(1))) void*)src,                  \
          (__attribute__((address_space(3))) void*)dst, 16, 0, 0);             \
    }                                                                          \
  }

#define LDV(p) (*reinterpret_cast<const bf16x8*>(p))
#define MM(A, Bf, C) __builtin_amdgcn_mfma_f32_16x16x32_bf16((A), (Bf), (C), 0, 0, 0)

  // 4x ds_read_b128: B-quad (kk = KB..KB+3) at BASE (incl. cf offset).
#define READS(BF, BASE)                                                        \
  BF[0] = LDV(BASE);                                                           \
  BF[1] = LDV((BASE) + 2048);                                                  \
  BF[2] = LDV((BASE) + 4096);                                                  \
  BF[3] = LDV((BASE) + 6144);

  // 16 MFMA: quad KB..KB+3 x rf0..3; FIRST starts acc from zerov.
#define MFMA_QUAD(ACC, BF, KB, FIRST)                                          \
  {                                                                            \
    if (FIRST) {                                                               \
      ACC[0] = MM(afrag[0][KB], BF[0], zerov);                                 \
      ACC[1] = MM(afrag[1][KB], BF[0], zerov);                                 \
      ACC[2] = MM(afrag[2][KB], BF[0], zerov);                                 \
      ACC[3] = MM(afrag[3][KB], BF[0], zerov);                                 \
    } else {                                                                   \
      ACC[0] = MM(afrag[0][KB], BF[0], ACC[0]);                                \
      ACC[1] = MM(afrag[1][KB], BF[0], ACC[1]);                                \
      ACC[2] = MM(afrag[2][KB], BF[0], ACC[2]);                                \
      ACC[3] = MM(afrag[3][KB], BF[0], ACC[3]);                                \
    }                                                                          \
    _Pragma("unroll")                                                          \
    for (int kq = 1; kq < 4; ++kq) {                                           \
      ACC[0] = MM(afrag[0][(KB) + kq], BF[kq], ACC[0]);                        \
      ACC[1] = MM(afrag[1][(KB) + kq], BF[kq], ACC[1]);                        \
      ACC[2] = MM(afrag[2][(KB) + kq], BF[kq], ACC[2]);                        \
      ACC[3] = MM(afrag[3][(KB) + kq], BF[kq], ACC[3]);                        \
    }                                                                          \
  }

#define EPI16(ACC)                                                             \
  {                                                                            \
    _Pragma("unroll")                                                          \
    for (int e = 0; e < 16; ++e)                                               \
      psum[e >> 2][e & 3] += __builtin_amdgcn_exp2f(ACC[e >> 2][e & 3]);       \
  }

#define BAR()  do { asm volatile("" ::: "memory");                             \
                    __builtin_amdgcn_s_barrier();                              \
                    asm volatile("" ::: "memory"); } while (0)
#define LGKM0_SB()                                                             \
  do { asm volatile("s_waitcnt lgkmcnt(0)" ::: "memory");                      \
       __builtin_amdgcn_sched_barrier(0); } while (0)

  float psum[4][4];
#pragma unroll
  for (int rf = 0; rf < 4; ++rf)
#pragma unroll
    for (int q = 0; q < 4; ++q) psum[rf][q] = 0.f;

  const f32x4 zerov = {0.f, 0.f, 0.f, 0.f};
  bf16x8 bfp[4], bfq[4];
  f32x4 accA[4], accB[4];
  accB[0] = zerov; accB[1] = zerov; accB[2] = zerov; accB[3] = zerov;  // dummy

  STAGE(0);
  STAGE(1);
  STAGE(2);
  asm volatile("s_waitcnt vmcnt(4)" ::: "memory");   // panel 0 landed
  BAR();

  for (int it = 0; it < 16; ++it) {
    const char* pbase = smem + ((it & 3) << 14) + vbase;
    // ---- P0: (cf0, kk0-3) ----
    READS(bfp, pbase);
    EPI16(accB);                       // prev panel's cf1 (dummy at it=0)
    if (it <= 12) STAGE(it + 3);
    BAR();
    LGKM0_SB();
    __builtin_amdgcn_s_setprio(1);
    MFMA_QUAD(accA, bfp, 0, true);
    __builtin_amdgcn_s_setprio(0);
    BAR();
    // ---- P1: (cf0, kk4-7) ----
    READS(bfq, pbase + 8192);
    BAR();
    LGKM0_SB();
    __builtin_amdgcn_s_setprio(1);
    MFMA_QUAD(accA, bfq, 4, false);
    __builtin_amdgcn_s_setprio(0);
    BAR();
    // ---- P2: (cf1, kk0-3) ----
    READS(bfp, pbase + 256);
    EPI16(accA);                       // accA completed at end of P1
    BAR();
    LGKM0_SB();
    __builtin_amdgcn_s_setprio(1);
    MFMA_QUAD(accB, bfp, 0, true);
    __builtin_amdgcn_s_setprio(0);
    BAR();
    // ---- P3: (cf1, kk4-7) ----
    READS(bfq, pbase + 256 + 8192);
    BAR();
    LGKM0_SB();
    __builtin_amdgcn_s_setprio(1);
    MFMA_QUAD(accB, bfq, 4, false);
    __builtin_amdgcn_s_setprio(0);
    // Staging guarantee for panel it+1 (counted; never 0 in steady state).
    if (it <= 12)      asm volatile("s_waitcnt vmcnt(4)" ::: "memory");
    else if (it == 13) asm volatile("s_waitcnt vmcnt(2)" ::: "memory");
    else if (it == 14) asm volatile("s_waitcnt vmcnt(0)" ::: "memory");
    BAR();
  }
  EPI16(accB);   // last panel's cf1

  // Reduce over the 16 column-lanes; -1.0 compensates the dummy epilogue.
#pragma unroll
  for (int rf = 0; rf < 4; ++rf)
#pragma unroll
    for (int q = 0; q < 4; ++q) {
      float s = psum[rf][q] - 1.0f;
      s += __shfl_xor(s, 1);
      s += __shfl_xor(s, 2);
      s += __shfl_xor(s, 4);
      s += __shfl_xor(s, 8);
      if (ar == 0)
        atomicAdd(rowsum + row0 + rf * 16 + g * 4 + q, s);
    }
#undef STAGE
#undef READS
#undef MFMA_QUAD
#undef EPI16
#undef BAR
#undef LGKM0_SB
#undef MM
#undef LDV
}

// ---------------------------------------------------------------------------
// 3) loss (unchanged from R10).
// ---------------------------------------------------------------------------
__global__ void __launch_bounds__(512) loss_kernel(
    const float* __restrict__ rowsum, const float* __restrict__ diag,
    float* __restrict__ out) {
  __shared__ float sh[8];
  int i = blockIdx.x * 512 + threadIdx.x;    // exactly covers 8192 rows
  float acc = logf(rowsum[i]) - diag[i];
#pragma unroll
  for (int m = 32; m; m >>= 1) acc += __shfl_xor(acc, m);
  if ((threadIdx.x & 63) == 0) sh[threadIdx.x >> 6] = acc;
  __syncthreads();
  if (threadIdx.x == 0) {
    float t = 0.f;
#pragma unroll
    for (int j = 0; j < 8; ++j) t += sh[j];
    atomicAdd(out, t / (float)N_ROWS);
  }
}

// ---------------------------------------------------------------------------
extern "C" void kernel_launch(void* const* d_in, const int* in_sizes, int n_in,
                              void* d_out, int out_size, void* d_ws, size_t ws_size,
                              hipStream_t stream) {
  const float* anc = (const float*)d_in[0];
  const float* pos = (const float*)d_in[1];
  const float* neg = (const float*)d_in[2];
  char* ws = (char*)d_ws;
  __hip_bfloat16* a_n = (__hip_bfloat16*)ws;                 // [8192][256] bf16 row-major
  __hip_bfloat16* p_k = a_n + (size_t)N_ROWS * DIM;          // k-major panels
  __hip_bfloat16* n_k = p_k + (size_t)N_ROWS * DIM;
  float* diag = (float*)(ws + (size_t)3 * N_ROWS * DIM * 2); // 8192 f32
  float* rowsum = diag + N_ROWS;                             // 8192 f32
  float* out = (float*)d_out;

  prep_kernel<<<2048 + 512, 256, 0, stream>>>(anc, pos, neg, a_n, p_k, n_k, diag, rowsum, out);
  fused_kernel<<<16 * 32, 512, 0, stream>>>(a_n, p_k, n_k, rowsum);
  loss_kernel<<<16, 512, 0, stream>>>(rowsum, diag, out);
}

// Round 13
// 59.002 us; speedup vs baseline: 2.1020x; 1.5136x over previous
//
#include <hip/hip_runtime.h>
#include <hip/hip_bf16.h>

#define N_ROWS 8192
#define DIM 256
#define TEMP_INV 20.0f
// logit2 = cos * 20*log2(e); with int8 quantized (x127) operands the exact
// i32 dot is converted via C2F = 20*log2(e)/127^2, then exp2.
#define C2F 1.7889516e-3f

typedef __attribute__((ext_vector_type(4))) int i32x4;

// ---------------------------------------------------------------------------
// 1) Merged prep (int8 quantization).
//    blocks [0,2048): anchor rows -- a8[i] = rint(127*anc[i]/||anc[i]||) (i8,
//                     row-major), diag = cos(anc,pos)/TEMP (f32 originals),
//                     rowsum = 0.
//    blocks [2048,2560): P/N panels -- normalize, quantize i8, transpose to
//                     k-major panels: 32 cols, byte(k,col) = (k/16)*512 +
//                     col*16 + (k%16)  (8KB/panel). Fused reads of this
//                     layout are linear-in-lane -> 0 LDS conflicts, and
//                     staging is a contiguous 8KB global_load_lds.
//    block 2559 thread 0 zero-inits out[0].
// ---------------------------------------------------------------------------
__global__ void __launch_bounds__(256) prep_kernel(
    const float* __restrict__ anc, const float* __restrict__ pos,
    const float* __restrict__ neg, char* __restrict__ a8,
    char* __restrict__ p8, char* __restrict__ n8,
    float* __restrict__ diag, float* __restrict__ rowsum,
    float* __restrict__ out) {
  __shared__ __align__(16) char t8[8192];   // one k-major i8 panel
  const int lane = threadIdx.x & 63;
  const int w = threadIdx.x >> 6;

  if (blockIdx.x < 2048) {                   // ---- anchor rows ----
    int wid = blockIdx.x * 4 + w;            // row 0..8191
    float4 a = reinterpret_cast<const float4*>(anc + (size_t)wid * DIM)[lane];
    float4 p = reinterpret_cast<const float4*>(pos + (size_t)wid * DIM)[lane];
    float d  = a.x * p.x + a.y * p.y + a.z * p.z + a.w * p.w;
    float na = a.x * a.x + a.y * a.y + a.z * a.z + a.w * a.w;
    float np = p.x * p.x + p.y * p.y + p.z * p.z + p.w * p.w;
#pragma unroll
    for (int m = 32; m; m >>= 1) {
      d  += __shfl_xor(d, m);
      na += __shfl_xor(na, m);
      np += __shfl_xor(np, m);
    }
    float rna = fmaxf(sqrtf(na), 1e-8f);
    float s = 127.0f / rna;
    int q0 = (int)rintf(a.x * s), q1 = (int)rintf(a.y * s);
    int q2 = (int)rintf(a.z * s), q3 = (int)rintf(a.w * s);
    unsigned pk = (q0 & 0xFF) | ((q1 & 0xFF) << 8) |
                  ((q2 & 0xFF) << 16) | ((q3 & 0xFF) << 24);
    *reinterpret_cast<unsigned*>(a8 + (size_t)wid * DIM + (lane << 2)) = pk;
    if (lane == 0) {
      diag[wid] = TEMP_INV * d / (rna * fmaxf(sqrtf(np), 1e-8f));
      rowsum[wid] = 0.f;
    }
    return;
  }
  // ---- P/N k-major i8 panels ----
  const int b = blockIdx.x - 2048;           // 0..511
  if (b == 511 && threadIdx.x == 0) out[0] = 0.f;
  const float* src = (b < 256) ? pos : neg;
  char* dst = (b < 256) ? p8 : n8;
  const int pb = b & 255;
#pragma unroll
  for (int i = 0; i < 8; ++i) {
    int r = i * 4 + w;                       // row (col of B) within panel
    float4 v = reinterpret_cast<const float4*>(src + (size_t)(pb * 32 + r) * DIM)[lane];
    float ss = v.x * v.x + v.y * v.y + v.z * v.z + v.w * v.w;
#pragma unroll
    for (int m = 32; m; m >>= 1) ss += __shfl_xor(ss, m);
    float s = 127.0f / fmaxf(sqrtf(ss), 1e-8f);
    int q0 = (int)rintf(v.x * s), q1 = (int)rintf(v.y * s);
    int q2 = (int)rintf(v.z * s), q3 = (int)rintf(v.w * s);
    unsigned pk = (q0 & 0xFF) | ((q1 & 0xFF) << 8) |
                  ((q2 & 0xFF) << 16) | ((q3 & 0xFF) << 24);
    // lane holds k = 4*lane..4*lane+3 -> k0 = lane>>2, off = 4*(lane&3)
    *reinterpret_cast<unsigned*>(t8 + ((lane >> 2) << 9) + (r << 4) +
                                 ((lane & 3) << 2)) = pk;
  }
  __syncthreads();
  const uint4* ts = reinterpret_cast<const uint4*>(t8);
  uint4* outp = reinterpret_cast<uint4*>(dst + (size_t)pb * 8192);
  outp[threadIdx.x]       = ts[threadIdx.x];
  outp[threadIdx.x + 256] = ts[threadIdx.x + 256];
}

// ---------------------------------------------------------------------------
// 2) Fused GEMM + row-sum(exp2) -- INT8 MFMA (16x16x64_i8, ~2x bf16 rate).
//    Rationale (R11 ablation + R12): bf16 schedule family exhausted at
//    73-82us (stream floor 39.6us, delivery tax ~35us). i8 halves/quarters
//    everything: MFMA pipe floor 17.4us, A-frags 64 VGPR (was 128), panels
//    8KB, 8 ds_read_b128/panel/wave. Lower regs (~140) unlock 3 blocks/CU
//    via __launch_bounds__(256,3) -- R3's multi-barrier-domain overlap (the
//    best observed MfmaUtil) now applies.
//    Grid: 32 rb (BM=256) x 32 cc = 1024 blocks -> 3/CU resident. Block:
//    4 waves; wave owns 64 rows (A = 4rf x 4km i32x4, pinned). Ring-4 8KB
//    panels (32KB LDS), STAGE = 2 global_load_lds/wave/panel, counted
//    vmcnt(4) steady (tail 2/0), ONE barrier per panel, compiler-scheduled
//    lgkmcnt. i32 dot is EXACT; epilogue exp2f(acc * C2F).
//    k-major panels -> ds_reads linear-in-lane, 0 conflicts.
//    MFMA C layout (shape-determined, dtype-independent, verified):
//    col=lane&15, row=(lane>>4)*4+q.
// ---------------------------------------------------------------------------
__global__ void __launch_bounds__(256, 3) fused_kernel(
    const char* __restrict__ a8, const char* __restrict__ p8,
    const char* __restrict__ n8, float* __restrict__ rowsum) {
  __shared__ __align__(16) char smem[4 * 8192];   // ring of 4 x 8KB panels
  const int tid  = threadIdx.x;
  const int lane = tid & 63;
  const int w    = tid >> 6;          // 0..3
  const int rb   = blockIdx.x >> 5;   // 0..31 (256 rows each)
  const int cc   = blockIdx.x & 31;   // 0..31 (512 cols = 16 panels each)
  const char* B = (cc < 16) ? (p8 + (size_t)cc * 16 * 8192)
                            : (n8 + (size_t)(cc - 16) * 16 * 8192);
  const int row0 = rb * 256 + w * 64;
  const int ar = lane & 15;           // fragment row/col index
  const int g  = lane >> 4;           // k-group within fragment
  const int vbase = (g << 9) + (ar << 4);  // lane byte-offset within a panel

  // A fragments: 64 rows x K=256 i8 = 4rf x 4km x i32x4 (64 VGPR, pinned).
  i32x4 af[4][4];
#pragma unroll
  for (int rf = 0; rf < 4; ++rf)
#pragma unroll
    for (int km = 0; km < 4; ++km) {
      af[rf][km] = *reinterpret_cast<const i32x4*>(
          a8 + (size_t)(row0 + rf * 16 + ar) * DIM + km * 64 + g * 16);
      asm volatile("" : "+v"(af[rf][km]));   // non-remat def: stays resident
    }

  // Stage panel `p` (8KB contiguous) into ring slot p&3: 2 loads/wave.
#define STAGE(p)                                                               \
  {                                                                            \
    _Pragma("unroll")                                                          \
    for (int j = 0; j < 2; ++j) {                                              \
      const int L = (w << 1) | j;                                              \
      const char* src = B + ((size_t)(p) << 13) + (L << 10) + (lane << 4);     \
      char* dst = (char*)smem + (((p) & 3) << 13) + (L << 10);                 \
      __builtin_amdgcn_global_load_lds(                                        \
          (const __attribute__((address_space(1))) void*)src,                  \
          (__attribute__((address_space(3))) void*)dst, 16, 0, 0);             \
    }                                                                          \
  }

#define MMI(A, Bf, C) __builtin_amdgcn_mfma_i32_16x16x64_i8((A), (Bf), (C), 0, 0, 0)

  // One cf-cluster: 4 ds_read_b128 + 16 MFMA + 16-elem exp2 epilogue.
#define CLUSTER(CFOFF)                                                         \
  {                                                                            \
    i32x4 bf[4];                                                               \
    _Pragma("unroll")                                                          \
    for (int km = 0; km < 4; ++km)                                             \
      bf[km] = *reinterpret_cast<const i32x4*>(pbase + (km << 11) + (CFOFF));  \
    i32x4 acc[4];                                                              \
    _Pragma("unroll")                                                          \
    for (int rf = 0; rf < 4; ++rf) acc[rf] = MMI(af[rf][0], bf[0], zeroi);     \
    _Pragma("unroll")                                                          \
    for (int km = 1; km < 4; ++km)                                             \
      _Pragma("unroll")                                                        \
      for (int rf = 0; rf < 4; ++rf)                                           \
        acc[rf] = MMI(af[rf][km], bf[km], acc[rf]);                            \
    _Pragma("unroll")                                                          \
    for (int rf = 0; rf < 4; ++rf)                                             \
      _Pragma("unroll")                                                        \
      for (int q = 0; q < 4; ++q)                                              \
        psum[rf][q] += __builtin_amdgcn_exp2f((float)acc[rf][q] * C2F);        \
  }

  float psum[4][4];
#pragma unroll
  for (int rf = 0; rf < 4; ++rf)
#pragma unroll
    for (int q = 0; q < 4; ++q) psum[rf][q] = 0.f;
  const i32x4 zeroi = {0, 0, 0, 0};

  STAGE(0);
  STAGE(1);
  STAGE(2);   // 6 loads/wave outstanding
  for (int it = 0; it < 16; ++it) {
    // Counted waits: own panel-`it` loads done; newer panels stay in flight.
    if (it <= 13)      asm volatile("s_waitcnt vmcnt(4)" ::: "memory");
    else if (it == 14) asm volatile("s_waitcnt vmcnt(2)" ::: "memory");
    else               asm volatile("s_waitcnt vmcnt(0)" ::: "memory");
    __builtin_amdgcn_s_barrier();
    const char* pbase = smem + ((it & 3) << 13) + vbase;
    CLUSTER(0);                      // cf0 (cols ar)
    if (it <= 12) STAGE(it + 3);     // overwrites slot (it-1)&3: reads retired
    CLUSTER(256);                    // cf1 (cols 16+ar)
  }

  // Reduce over the 16 column-lanes (vary ar, keep g); accumulate per row.
#pragma unroll
  for (int rf = 0; rf < 4; ++rf)
#pragma unroll
    for (int q = 0; q < 4; ++q) {
      float s = psum[rf][q];
      s += __shfl_xor(s, 1);
      s += __shfl_xor(s, 2);
      s += __shfl_xor(s, 4);
      s += __shfl_xor(s, 8);
      if (ar == 0)
        atomicAdd(rowsum + row0 + rf * 16 + g * 4 + q, s);
    }
#undef STAGE
#undef CLUSTER
#undef MMI
}

// ---------------------------------------------------------------------------
// 3) loss: grid 16 x 512 thr, one row per thread;
//    out[0] (+)= block-partials / N   (out zero-initialized in prep).
// ---------------------------------------------------------------------------
__global__ void __launch_bounds__(512) loss_kernel(
    const float* __restrict__ rowsum, const float* __restrict__ diag,
    float* __restrict__ out) {
  __shared__ float sh[8];
  int i = blockIdx.x * 512 + threadIdx.x;    // exactly covers 8192 rows
  float acc = logf(rowsum[i]) - diag[i];
#pragma unroll
  for (int m = 32; m; m >>= 1) acc += __shfl_xor(acc, m);
  if ((threadIdx.x & 63) == 0) sh[threadIdx.x >> 6] = acc;
  __syncthreads();
  if (threadIdx.x == 0) {
    float t = 0.f;
#pragma unroll
    for (int j = 0; j < 8; ++j) t += sh[j];
    atomicAdd(out, t / (float)N_ROWS);
  }
}

// ---------------------------------------------------------------------------
extern "C" void kernel_launch(void* const* d_in, const int* in_sizes, int n_in,
                              void* d_out, int out_size, void* d_ws, size_t ws_size,
                              hipStream_t stream) {
  const float* anc = (const float*)d_in[0];
  const float* pos = (const float*)d_in[1];
  const float* neg = (const float*)d_in[2];
  char* ws = (char*)d_ws;
  char* a8 = ws;                                  // [8192][256] i8 row-major
  char* p8 = ws + (size_t)N_ROWS * DIM;           // k-major i8 panels (2MB)
  char* n8 = p8 + (size_t)N_ROWS * DIM;
  float* diag = (float*)(ws + (size_t)3 * N_ROWS * DIM);  // 8192 f32
  float* rowsum = diag + N_ROWS;                          // 8192 f32
  float* out = (float*)d_out;

  prep_kernel<<<2048 + 512, 256, 0, stream>>>(anc, pos, neg, a8, p8, n8, diag, rowsum, out);
  fused_kernel<<<32 * 32, 256, 0, stream>>>(a8, p8, n8, rowsum);
  loss_kernel<<<16, 512, 0, stream>>>(rowsum, diag, out);
}